// Round 3
// baseline (535.345 us; speedup 1.0000x reference)
//
#include <hip/hip_runtime.h>

typedef float f32x4 __attribute__((ext_vector_type(4)));
typedef float f32x16 __attribute__((ext_vector_type(16)));
typedef __bf16 bf16x8 __attribute__((ext_vector_type(8)));
typedef unsigned int u32x4 __attribute__((ext_vector_type(4)));
typedef unsigned short ushort_t;

// ---------------------------------------------------------------- fp32 -> bf16 (RNE)
__device__ __forceinline__ unsigned short f2bf(float f) {
    unsigned u = __float_as_uint(f);
    u += 0x7FFFu + ((u >> 16) & 1u);   // round-nearest-even (inputs finite)
    return (unsigned short)(u >> 16);
}

// Fused cast for x and W. Split at thread 4194304 = block 16384 -> wave-uniform branch.
// Nontemporal loads: fp32 inputs are dead after this; keep L2/L3 for the bf16 the GEMM re-reads.
// R2 verified: cast ~50 us (near BW); also warms L2/L3 -> GEMM fetch served faster.
__global__ __launch_bounds__(256) void cast_both(const f32x4* __restrict__ x, u32x4* __restrict__ xo,
                                                 const f32x4* __restrict__ w, u32x4* __restrict__ wo) {
    long t = (long)blockIdx.x * 256 + threadIdx.x;
    const f32x4* src;
    u32x4* dst;
    long j;
    if (t < 4194304L) { src = x; dst = xo; j = t; }
    else              { src = w; dst = wo; j = t - 4194304L; }
    f32x4 a = __builtin_nontemporal_load(&src[2 * j]);
    f32x4 b = __builtin_nontemporal_load(&src[2 * j + 1]);
    u32x4 v;
    v.x = (unsigned)f2bf(a.x) | ((unsigned)f2bf(a.y) << 16);
    v.y = (unsigned)f2bf(a.z) | ((unsigned)f2bf(a.w) << 16);
    v.z = (unsigned)f2bf(b.x) | ((unsigned)f2bf(b.y) << 16);
    v.w = (unsigned)f2bf(b.z) | ((unsigned)f2bf(b.w) << 16);
    dst[j] = v;   // cached store: GEMM re-reads from L2/L3
}

// ---------------------------------------------------------------- bf16 MFMA GEMM (B^T layout)
// out[m,n] = sum_k A[m,k]*B[n,k] + bias[n].  A:[M,K] bf16 row-major, B:[N,K] bf16 row-major.
// Block tile 128x128, BK=64, 4 waves (2x2), each wave 64x64 via 2x2 of 32x32x16 MFMA.
// R3 change: 16x16x32 -> 32x32x16 (same LDS traffic, half the MFMA instructions,
// ~17% fewer matrix-pipe cycles, 15% higher ubench ceiling).
// LDS staging identical to R1/R2 (verified, 0 bank conflicts): global_load_lds width=16,
// XOR swizzle: 16B block kb of row r stored at slot kb ^ (r&7).
constexpr int KDIM = 4096;

__global__ __launch_bounds__(256, 5) void gemm_bf16_mfma(const ushort_t* __restrict__ A,
                                                         const ushort_t* __restrict__ B,
                                                         const float* __restrict__ bias,
                                                         float* __restrict__ out) {
    __shared__ ushort_t As[128 * 64];   // 16 KB
    __shared__ ushort_t Bs[128 * 64];   // 16 KB

    const int tid  = threadIdx.x;
    const int lane = tid & 63;
    const int wave = tid >> 6;
    const int wm   = (wave >> 1) * 64;  // wave row offset in tile
    const int wn   = (wave & 1) * 64;   // wave col offset in tile
    const int half = lane >> 5;         // 0..1 (K-half selector for 32x32x16 frags)
    const int ml   = lane & 31;         // row/col within 32-block

    const int m0 = blockIdx.y * 128;
    const int n0 = blockIdx.x * 128;

    // staging: load inst i, thread tid -> LDS 16B slot (i*256 + tid)
    //   row = i*32 + tid/8 ; stored slot col = tid&7 ; source block kb = (tid&7) ^ (row&7)
    const int srow = tid >> 3;
    const int kb   = (tid & 7) ^ (srow & 7);
    const ushort_t* ga = A + (size_t)(m0 + srow) * KDIM + kb * 8;
    const ushort_t* gb = B + (size_t)(n0 + srow) * KDIM + kb * 8;
    char* lAs = (char*)As;
    char* lBs = (char*)Bs;
    const int ldst = tid * 16;

    f32x16 acc[2][2];
#pragma unroll
    for (int i = 0; i < 2; ++i)
#pragma unroll
        for (int j = 0; j < 2; ++j)
#pragma unroll
            for (int r = 0; r < 16; ++r) acc[i][j][r] = 0.f;

    for (int k0 = 0; k0 < KDIM; k0 += 64) {
        __syncthreads();   // previous tile fully consumed
#pragma unroll
        for (int i = 0; i < 4; ++i)
            __builtin_amdgcn_global_load_lds(
                (const __attribute__((address_space(1))) unsigned int*)(ga + (size_t)i * 32 * KDIM + k0),
                (__attribute__((address_space(3))) unsigned int*)(lAs + i * 4096 + ldst),
                16, 0, 0);
#pragma unroll
        for (int i = 0; i < 4; ++i)
            __builtin_amdgcn_global_load_lds(
                (const __attribute__((address_space(1))) unsigned int*)(gb + (size_t)i * 32 * KDIM + k0),
                (__attribute__((address_space(3))) unsigned int*)(lBs + i * 4096 + ldst),
                16, 0, 0);
        __syncthreads();   // vmcnt(0) drain -> data visible

#pragma unroll
        for (int s = 0; s < 4; ++s) {     // four K=16 steps per BK=64 tile
            const int kbb = 2 * s + half; // 16B block along K for this lane's K-half
            bf16x8 av[2], bv[2];
#pragma unroll
            for (int t = 0; t < 2; ++t) {
                const int row = wm + t * 32 + ml;
                const int sw  = (kbb ^ (row & 7)) << 4;
                av[t] = *(const bf16x8*)(lAs + row * 128 + sw);
            }
#pragma unroll
            for (int t = 0; t < 2; ++t) {
                const int row = wn + t * 32 + ml;
                const int sw  = (kbb ^ (row & 7)) << 4;
                bv[t] = *(const bf16x8*)(lBs + row * 128 + sw);
            }
#pragma unroll
            for (int i = 0; i < 2; ++i)
#pragma unroll
                for (int j = 0; j < 2; ++j)
                    acc[i][j] = __builtin_amdgcn_mfma_f32_32x32x16_bf16(av[i], bv[j], acc[i][j], 0, 0, 0);
        }
    }

    // epilogue: 32x32 C/D layout (HW-verified m74/m101):
    //   col = lane&31, row = (reg&3) + 8*(reg>>2) + 4*(lane>>5)
    float bb[2];
#pragma unroll
    for (int j = 0; j < 2; ++j) bb[j] = bias[n0 + wn + j * 32 + ml];

#pragma unroll
    for (int i = 0; i < 2; ++i) {
#pragma unroll
        for (int j = 0; j < 2; ++j) {
            const int gc = n0 + wn + j * 32 + ml;
#pragma unroll
            for (int g = 0; g < 4; ++g) {
#pragma unroll
                for (int r = 0; r < 4; ++r) {
                    const int gr = m0 + wm + i * 32 + g * 8 + half * 4 + r;
                    out[(size_t)gr * 4096 + gc] = acc[i][j][4 * g + r] + bb[j];
                }
            }
        }
    }
}

// ---------------------------------------------------------------- fp32 fallback (only if ws too small)
__global__ __launch_bounds__(256) void gemm_f32_fallback(const float* __restrict__ x,
                                                         const float* __restrict__ W,
                                                         const float* __restrict__ bias,
                                                         float* __restrict__ out) {
    __shared__ float As[32][33];
    __shared__ float Bs[32][33];
    const int tx = threadIdx.x & 31, ty = threadIdx.x >> 5;   // ty 0..7
    const int m0 = blockIdx.y * 32, n0 = blockIdx.x * 32;
    float acc[4] = {0.f, 0.f, 0.f, 0.f};
    for (int k0 = 0; k0 < 4096; k0 += 32) {
#pragma unroll
        for (int i = 0; i < 4; ++i) {
            As[ty + 8 * i][tx] = x[(size_t)(m0 + ty + 8 * i) * 4096 + k0 + tx];
            Bs[ty + 8 * i][tx] = W[(size_t)(n0 + ty + 8 * i) * 4096 + k0 + tx];
        }
        __syncthreads();
#pragma unroll 8
        for (int kk = 0; kk < 32; ++kk) {
            const float bv = Bs[tx][kk];
#pragma unroll
            for (int i = 0; i < 4; ++i) acc[i] += As[ty + 8 * i][kk] * bv;
        }
        __syncthreads();
    }
#pragma unroll
    for (int i = 0; i < 4; ++i)
        out[(size_t)(m0 + ty + 8 * i) * 4096 + n0 + tx] = acc[i] + bias[n0 + tx];
}

// ---------------------------------------------------------------- launch
extern "C" void kernel_launch(void* const* d_in, const int* in_sizes, int n_in,
                              void* d_out, int out_size, void* d_ws, size_t ws_size,
                              hipStream_t stream) {
    const float* x = (const float*)d_in[0];   // [8192, 4096]
    const float* W = (const float*)d_in[1];   // [4096, 4096]
    const float* b = (const float*)d_in[2];   // [4096]
    float* out = (float*)d_out;               // [8192, 4096]

    constexpr size_t T = 8192, DIN = 4096, DOUT = 4096;
    const size_t nx = T * DIN, nw = DOUT * DIN;

    if (ws_size >= (nx + nw) * sizeof(unsigned short)) {
        unsigned short* xbf = (unsigned short*)d_ws;
        unsigned short* wbf = xbf + nx;
        // total threads = nx/8 + nw/8 = 6291456 -> 24576 blocks of 256
        cast_both<<<24576, 256, 0, stream>>>((const f32x4*)x, (u32x4*)xbf,
                                             (const f32x4*)W, (u32x4*)wbf);
        dim3 grid(DOUT / 128, T / 128);   // 32 x 64 = 2048 blocks
        gemm_bf16_mfma<<<grid, 256, 0, stream>>>(xbf, wbf, b, out);
    } else {
        dim3 grid(DOUT / 32, T / 32);
        gemm_f32_fallback<<<grid, 256, 0, stream>>>(x, W, b, out);
    }
}